// Round 1
// baseline (516.185 us; speedup 1.0000x reference)
//
#include <hip/hip_runtime.h>
#include <hip/hip_bf16.h>
#include <cstdint>
#include <cstddef>

#define T_LEN 2048
#define BATCH 32
#define DIM 512
#define M_TOT (T_LEN * BATCH)   // 65536
#define K_DIM DIM               // 512
#define N1 (2 * DIM)            // 1024
#define NCHUNK 64
#define CLEN (T_LEN / NCHUNK)   // 32
#define BD (BATCH * DIM)        // 16384

typedef unsigned short ushort_t;
typedef __attribute__((ext_vector_type(8))) short short8;
typedef __attribute__((ext_vector_type(4))) float floatx4;
typedef __attribute__((ext_vector_type(4))) unsigned short ushort4v;

__device__ __forceinline__ float bf2f(ushort_t u) {
  union { unsigned int i; float f; } v;
  v.i = ((unsigned int)u) << 16;
  return v.f;
}
__device__ __forceinline__ ushort_t f2bf(float f) {
  union { float f; unsigned int i; } v;
  v.f = f;
  unsigned int x = v.i;
  return (ushort_t)((x + 0x7fffu + ((x >> 16) & 1u)) >> 16);
}

__device__ __forceinline__ void async16(const void* gp, void* lp) {
  __builtin_amdgcn_global_load_lds(
      (__attribute__((address_space(1))) void*)(void*)gp,
      (__attribute__((address_space(3))) void*)lp, 16, 0, 0);
}

// ---------------- convert fp32 -> bf16 (vector x4) ----------------
__global__ __launch_bounds__(256) void cvt_f32_bf16(const float* __restrict__ in,
                                                    ushort_t* __restrict__ out,
                                                    int n4) {
  int i = blockIdx.x * 256 + threadIdx.x;
  if (i >= n4) return;
  const floatx4 v = *((const floatx4*)in + i);
  ushort4v o;
  o.x = f2bf(v.x); o.y = f2bf(v.y); o.z = f2bf(v.z); o.w = f2bf(v.w);
  *((ushort4v*)out + i) = o;
}

// ---------------- bf16 MFMA GEMM, C = A[M,K] * B[N,K]^T ----------------
// 128x128 tile, BK=64, 256 threads (4 waves, 2x2), 16x16x32 MFMA.
// LDS: row-major [128][64] bf16, XOR-swizzled in 16B chunks: slot (r,c)
// holds global chunk (r, c ^ (r&7)) so ds_read_b128 frag reads are
// <=2-way bank aliased (free) while global_load_lds stays contiguous.
// MODE 0: in_proj epilogue (bias + gate): col<DIM -> Bz=Bvec*(v), else
//         gA=Avec*sigmoid(v). MODE 1: plain bias epilogue.
template <int MODE>
__global__ __launch_bounds__(256, 2) void gemm_bt(
    const ushort_t* __restrict__ Ag, const ushort_t* __restrict__ Bg,
    const float* __restrict__ bias, const float* __restrict__ Avec,
    const float* __restrict__ Bvec, ushort_t* __restrict__ out0,
    ushort_t* __restrict__ out1) {
  __shared__ __align__(16) ushort_t As[128 * 64];
  __shared__ __align__(16) ushort_t Bs[128 * 64];
  const int tid = threadIdx.x;
  const int lane = tid & 63;
  const int wid = tid >> 6;
  const int wave_m = wid >> 1;
  const int wave_n = wid & 1;
  const int m0 = blockIdx.x * 128;
  const int n0 = blockIdx.y * 128;

  floatx4 acc[4][4] = {};

  const int sr = tid >> 3;  // 0..31: row within a 32-row staging group
  const int sc = tid & 7;   // 16B chunk slot within the row

  for (int k0 = 0; k0 < K_DIM; k0 += 64) {
    __syncthreads();
#pragma unroll
    for (int i = 0; i < 4; i++) {
      const int r = i * 32 + sr;
      const int cg = sc ^ (r & 7);  // swizzled source chunk
      async16(Ag + (size_t)(m0 + r) * K_DIM + k0 + cg * 8,
              (char*)As + (i * 32 + wid * 8) * 128);
      async16(Bg + (size_t)(n0 + r) * K_DIM + k0 + cg * 8,
              (char*)Bs + (i * 32 + wid * 8) * 128);
    }
    __syncthreads();
#pragma unroll
    for (int kk = 0; kk < 2; kk++) {
      const int jc = kk * 4 + (lane >> 4);
      short8 af[4], bfr[4];
#pragma unroll
      for (int im = 0; im < 4; im++) {
        const int row = wave_m * 64 + im * 16 + (lane & 15);
        af[im] = *(const short8*)((const char*)As + row * 128 +
                                  ((jc ^ (row & 7)) * 16));
      }
#pragma unroll
      for (int in = 0; in < 4; in++) {
        const int row = wave_n * 64 + in * 16 + (lane & 15);
        bfr[in] = *(const short8*)((const char*)Bs + row * 128 +
                                   ((jc ^ (row & 7)) * 16));
      }
#pragma unroll
      for (int im = 0; im < 4; im++)
#pragma unroll
        for (int in = 0; in < 4; in++)
          acc[im][in] = __builtin_amdgcn_mfma_f32_16x16x32_bf16(
              af[im], bfr[in], acc[im][in], 0, 0, 0);
    }
  }

#pragma unroll
  for (int im = 0; im < 4; im++) {
#pragma unroll
    for (int in = 0; in < 4; in++) {
      const int col = n0 + wave_n * 64 + in * 16 + (lane & 15);
#pragma unroll
      for (int r = 0; r < 4; r++) {
        const int row = m0 + wave_m * 64 + im * 16 + (lane >> 4) * 4 + r;
        float val = acc[im][in][r] + bias[col];
        if (MODE == 0) {
          if (col < DIM) {
            out0[(size_t)row * DIM + col] = f2bf(Bvec[col] * val);
          } else {
            const int d = col - DIM;
            const float s = 1.f / (1.f + __expf(-val));
            out1[(size_t)row * DIM + d] = f2bf(Avec[d] * s);
          }
        } else {
          out0[(size_t)row * DIM + col] = f2bf(val);
        }
      }
    }
  }
}

// ---------------- chunked scan ----------------
// h_t = a_t * h_{t-1} + bz_t, independent per (b,d) pair, t in [0,2048).
// Layout: element (t, bd) at flat index t*BD + bd. Each thread owns 4
// consecutive bd (ushort4 bf16 loads, coalesced across threads).

// Pass 1: per chunk, local scan from h=0; emit prod(a) and local h_end.
__global__ __launch_bounds__(256) void scan_pass1(
    const ushort_t* __restrict__ a_arr, const ushort_t* __restrict__ bz_arr,
    float* __restrict__ pout, float* __restrict__ hout) {
  const int tid = blockIdx.x * 256 + threadIdx.x;  // 64*4096 threads
  const int c = tid >> 12;
  const int q = tid & 4095;
  size_t base = (size_t)(c * CLEN) * BD + q * 4;
  float h0 = 0.f, h1 = 0.f, h2 = 0.f, h3 = 0.f;
  float p0 = 1.f, p1 = 1.f, p2 = 1.f, p3 = 1.f;
#pragma unroll 8
  for (int t = 0; t < CLEN; t++) {
    ushort4v av = *(const ushort4v*)(a_arr + base + (size_t)t * BD);
    ushort4v bv = *(const ushort4v*)(bz_arr + base + (size_t)t * BD);
    float a0 = bf2f(av.x), a1 = bf2f(av.y), a2 = bf2f(av.z), a3 = bf2f(av.w);
    h0 = a0 * h0 + bf2f(bv.x); p0 *= a0;
    h1 = a1 * h1 + bf2f(bv.y); p1 *= a1;
    h2 = a2 * h2 + bf2f(bv.z); p2 *= a2;
    h3 = a3 * h3 + bf2f(bv.w); p3 *= a3;
  }
  const size_t ci = (size_t)c * BD + q * 4;
  *(floatx4*)(pout + ci) = (floatx4){p0, p1, p2, p3};
  *(floatx4*)(hout + ci) = (floatx4){h0, h1, h2, h3};
}

// Pass 2: sequentially combine chunk carries; carry[c] = h entering chunk c.
__global__ __launch_bounds__(256) void scan_pass2(
    const float* __restrict__ p, const float* __restrict__ hend,
    float* __restrict__ carry) {
  const int q = blockIdx.x * 256 + threadIdx.x;  // 4096 threads
  float h0 = 0.f, h1 = 0.f, h2 = 0.f, h3 = 0.f;
  for (int c = 0; c < NCHUNK; c++) {
    const size_t ci = (size_t)c * BD + q * 4;
    floatx4 pv = *(const floatx4*)(p + ci);
    floatx4 hv = *(const floatx4*)(hend + ci);
    *(floatx4*)(carry + ci) = (floatx4){h0, h1, h2, h3};
    h0 = hv.x + pv.x * h0;
    h1 = hv.y + pv.y * h1;
    h2 = hv.z + pv.z * h2;
    h3 = hv.w + pv.w * h3;
  }
}

// Pass 3: re-scan each chunk with its carry-in, write h (bf16).
__global__ __launch_bounds__(256) void scan_pass3(
    const ushort_t* __restrict__ a_arr, const ushort_t* __restrict__ bz_arr,
    const float* __restrict__ carry, ushort_t* __restrict__ h_arr) {
  const int tid = blockIdx.x * 256 + threadIdx.x;
  const int c = tid >> 12;
  const int q = tid & 4095;
  size_t base = (size_t)(c * CLEN) * BD + q * 4;
  const size_t ci = (size_t)c * BD + q * 4;
  floatx4 cv = *(const floatx4*)(carry + ci);
  float h0 = cv.x, h1 = cv.y, h2 = cv.z, h3 = cv.w;
#pragma unroll 8
  for (int t = 0; t < CLEN; t++) {
    ushort4v av = *(const ushort4v*)(a_arr + base + (size_t)t * BD);
    ushort4v bv = *(const ushort4v*)(bz_arr + base + (size_t)t * BD);
    h0 = bf2f(av.x) * h0 + bf2f(bv.x);
    h1 = bf2f(av.y) * h1 + bf2f(bv.y);
    h2 = bf2f(av.z) * h2 + bf2f(bv.z);
    h3 = bf2f(av.w) * h3 + bf2f(bv.w);
    ushort4v o;
    o.x = f2bf(h0); o.y = f2bf(h1); o.z = f2bf(h2); o.w = f2bf(h3);
    *(ushort4v*)(h_arr + base + (size_t)t * BD) = o;
  }
}

// ---------------- residual + layernorm ----------------
// One wave per row of 512; lane handles 8 consecutive cols.
__global__ __launch_bounds__(256) void ln_kernel(
    const float* __restrict__ x, const ushort_t* __restrict__ op,
    const float* __restrict__ gamma, const float* __restrict__ beta,
    float* __restrict__ y) {
  const int wid = threadIdx.x >> 6;
  const int lane = threadIdx.x & 63;
  const size_t row = (size_t)blockIdx.x * 4 + wid;
  const size_t base = row * DIM + lane * 8;
  floatx4 x0 = *(const floatx4*)(x + base);
  floatx4 x1 = *(const floatx4*)(x + base + 4);
  short8 ov = *(const short8*)(op + base);
  float v[8];
  v[0] = x0.x + bf2f((ushort_t)ov[0]);
  v[1] = x0.y + bf2f((ushort_t)ov[1]);
  v[2] = x0.z + bf2f((ushort_t)ov[2]);
  v[3] = x0.w + bf2f((ushort_t)ov[3]);
  v[4] = x1.x + bf2f((ushort_t)ov[4]);
  v[5] = x1.y + bf2f((ushort_t)ov[5]);
  v[6] = x1.z + bf2f((ushort_t)ov[6]);
  v[7] = x1.w + bf2f((ushort_t)ov[7]);
  float s = 0.f, ss = 0.f;
#pragma unroll
  for (int j = 0; j < 8; j++) {
    s += v[j];
    ss += v[j] * v[j];
  }
#pragma unroll
  for (int m = 32; m >= 1; m >>= 1) {
    s += __shfl_xor(s, m, 64);
    ss += __shfl_xor(ss, m, 64);
  }
  const float mean = s * (1.f / DIM);
  const float var = ss * (1.f / DIM) - mean * mean;
  const float rstd = rsqrtf(var + 1e-5f);
  const int cb = lane * 8;
  floatx4 o0, o1;
  o0.x = (v[0] - mean) * rstd * gamma[cb + 0] + beta[cb + 0];
  o0.y = (v[1] - mean) * rstd * gamma[cb + 1] + beta[cb + 1];
  o0.z = (v[2] - mean) * rstd * gamma[cb + 2] + beta[cb + 2];
  o0.w = (v[3] - mean) * rstd * gamma[cb + 3] + beta[cb + 3];
  o1.x = (v[4] - mean) * rstd * gamma[cb + 4] + beta[cb + 4];
  o1.y = (v[5] - mean) * rstd * gamma[cb + 5] + beta[cb + 5];
  o1.z = (v[6] - mean) * rstd * gamma[cb + 6] + beta[cb + 6];
  o1.w = (v[7] - mean) * rstd * gamma[cb + 7] + beta[cb + 7];
  *(floatx4*)(y + base) = o0;
  *(floatx4*)(y + base + 4) = o1;
}

// ---------------- launch ----------------
extern "C" void kernel_launch(void* const* d_in, const int* in_sizes, int n_in,
                              void* d_out, int out_size, void* d_ws,
                              size_t ws_size, hipStream_t stream) {
  const float* x = (const float*)d_in[0];
  const float* W_in = (const float*)d_in[1];
  const float* b_in = (const float*)d_in[2];
  const float* W_out = (const float*)d_in[3];
  const float* b_out = (const float*)d_in[4];
  const float* Avec = (const float*)d_in[5];
  const float* Bvec = (const float*)d_in[6];
  const float* gamma = (const float*)d_in[7];
  const float* beta = (const float*)d_in[8];
  float* out = (float*)d_out;

  char* ws = (char*)d_ws;
  const size_t SZ64 = (size_t)M_TOT * DIM * 2;  // 64 MiB
  ushort_t* xb = (ushort_t*)ws;                  // x bf16; later reused as h
  ushort_t* gA = (ushort_t*)(ws + SZ64);         // gate*A; later reused as out_ws
  ushort_t* bz = (ushort_t*)(ws + 2 * SZ64);     // B*z
  ushort_t* wib = (ushort_t*)(ws + 3 * SZ64);
  ushort_t* wob = (ushort_t*)(ws + 3 * SZ64 + (size_t)N1 * K_DIM * 2);
  char* p0 = ws + 3 * SZ64 + (size_t)N1 * K_DIM * 2 + (size_t)DIM * K_DIM * 2;
  float* pc = (float*)p0;                                   // 4 MiB
  float* hc = (float*)(p0 + (size_t)NCHUNK * BD * 4);       // 4 MiB
  float* cc = (float*)(p0 + 2 * (size_t)NCHUNK * BD * 4);   // 4 MiB

  // converts
  cvt_f32_bf16<<<(M_TOT * DIM / 4 + 255) / 256, 256, 0, stream>>>(
      x, xb, M_TOT * DIM / 4);
  cvt_f32_bf16<<<(N1 * K_DIM / 4 + 255) / 256, 256, 0, stream>>>(
      W_in, wib, N1 * K_DIM / 4);
  cvt_f32_bf16<<<(DIM * K_DIM / 4 + 255) / 256, 256, 0, stream>>>(
      W_out, wob, DIM * K_DIM / 4);

  // in_proj + gate epilogue
  gemm_bt<0><<<dim3(M_TOT / 128, N1 / 128), 256, 0, stream>>>(
      xb, wib, b_in, Avec, Bvec, bz, gA);

  // chunked scan
  scan_pass1<<<NCHUNK * (BD / 4) / 256, 256, 0, stream>>>(gA, bz, pc, hc);
  scan_pass2<<<(BD / 4) / 256, 256, 0, stream>>>(pc, hc, cc);
  scan_pass3<<<NCHUNK * (BD / 4) / 256, 256, 0, stream>>>(gA, bz, cc, xb);

  // out_proj (h = xb region, output into gA region)
  gemm_bt<1><<<dim3(M_TOT / 128, DIM / 128), 256, 0, stream>>>(
      xb, wob, b_out, nullptr, nullptr, gA, nullptr);

  // residual + layernorm
  ln_kernel<<<M_TOT / 4, 256, 0, stream>>>(x, gA, gamma, beta, out);
}

// Round 2
// 493.045 us; speedup vs baseline: 1.0469x; 1.0469x over previous
//
#include <hip/hip_runtime.h>
#include <hip/hip_bf16.h>
#include <cstdint>
#include <cstddef>

#define T_LEN 2048
#define BATCH 32
#define DIM 512
#define M_TOT (T_LEN * BATCH)   // 65536
#define K_DIM DIM               // 512
#define N1 (2 * DIM)            // 1024
#define NCHUNK 64
#define CLEN (T_LEN / NCHUNK)   // 32
#define BD (BATCH * DIM)        // 16384
#define MT_TILES (M_TOT / 128)  // 512

typedef unsigned short ushort_t;
typedef __attribute__((ext_vector_type(8))) short short8;
typedef __attribute__((ext_vector_type(4))) float floatx4;
typedef __attribute__((ext_vector_type(4))) unsigned short ushort4v;

__device__ __forceinline__ float bf2f(ushort_t u) {
  union { unsigned int i; float f; } v;
  v.i = ((unsigned int)u) << 16;
  return v.f;
}
__device__ __forceinline__ ushort_t f2bf(float f) {
  union { float f; unsigned int i; } v;
  v.f = f;
  unsigned int x = v.i;
  return (ushort_t)((x + 0x7fffu + ((x >> 16) & 1u)) >> 16);
}

__device__ __forceinline__ void async16(const void* gp, void* lp) {
  __builtin_amdgcn_global_load_lds(
      (__attribute__((address_space(1))) void*)(void*)gp,
      (__attribute__((address_space(3))) void*)lp, 16, 0, 0);
}

// ---------------- convert fp32 -> bf16 (vector x4) ----------------
__global__ __launch_bounds__(256) void cvt_f32_bf16(const float* __restrict__ in,
                                                    ushort_t* __restrict__ out,
                                                    int n4) {
  int i = blockIdx.x * 256 + threadIdx.x;
  if (i >= n4) return;
  const floatx4 v = *((const floatx4*)in + i);
  ushort4v o;
  o.x = f2bf(v.x); o.y = f2bf(v.y); o.z = f2bf(v.z); o.w = f2bf(v.w);
  *((ushort4v*)out + i) = o;
}

// ---------------- bf16 MFMA GEMM, C = A[M,K] * B[N,K]^T ----------------
// 128x128 tile, BK=64, 256 threads (4 waves, 2x2), 16x16x32 MFMA.
// LDS: row-major [128][64] bf16, XOR-swizzled in 16B chunks.
// 1-D grid with XCD-aware swizzle: bid&7 selects XCD (assuming round-robin
// dispatch); each XCD owns a contiguous m-range; consecutive slots on one
// XCD iterate n-tiles of the SAME m-tile -> A-tile reuse hits that XCD's L2,
// and each A-tile is fetched from HBM exactly once. Weights stay L2-resident.
// MODE 0: in_proj epilogue (bias + gate). MODE 1: plain bias epilogue.
template <int MODE, int NT>
__global__ __launch_bounds__(256, 2) void gemm_bt(
    const ushort_t* __restrict__ Ag, const ushort_t* __restrict__ Bg,
    const float* __restrict__ bias, const float* __restrict__ Avec,
    const float* __restrict__ Bvec, ushort_t* __restrict__ out0,
    ushort_t* __restrict__ out1) {
  __shared__ __align__(16) ushort_t As[128 * 64];
  __shared__ __align__(16) ushort_t Bs[128 * 64];
  const int tid = threadIdx.x;
  const int lane = tid & 63;
  const int wid = tid >> 6;
  const int wave_m = wid >> 1;
  const int wave_n = wid & 1;

  const int bid = blockIdx.x;
  const int xcd = bid & 7;
  const int slot = bid >> 3;
  const int mt = xcd * (MT_TILES / 8) + slot / NT;
  const int nt = slot % NT;
  const int m0 = mt * 128;
  const int n0 = nt * 128;

  floatx4 acc[4][4] = {};

  const int sr = tid >> 3;  // 0..31: row within a 32-row staging group
  const int sc = tid & 7;   // 16B chunk slot within the row

  for (int k0 = 0; k0 < K_DIM; k0 += 64) {
    __syncthreads();
#pragma unroll
    for (int i = 0; i < 4; i++) {
      const int r = i * 32 + sr;
      const int cg = sc ^ (r & 7);  // swizzled source chunk
      async16(Ag + (size_t)(m0 + r) * K_DIM + k0 + cg * 8,
              (char*)As + (i * 32 + wid * 8) * 128);
      async16(Bg + (size_t)(n0 + r) * K_DIM + k0 + cg * 8,
              (char*)Bs + (i * 32 + wid * 8) * 128);
    }
    __syncthreads();
#pragma unroll
    for (int kk = 0; kk < 2; kk++) {
      const int jc = kk * 4 + (lane >> 4);
      short8 af[4], bfr[4];
#pragma unroll
      for (int im = 0; im < 4; im++) {
        const int row = wave_m * 64 + im * 16 + (lane & 15);
        af[im] = *(const short8*)((const char*)As + row * 128 +
                                  ((jc ^ (row & 7)) * 16));
      }
#pragma unroll
      for (int in = 0; in < 4; in++) {
        const int row = wave_n * 64 + in * 16 + (lane & 15);
        bfr[in] = *(const short8*)((const char*)Bs + row * 128 +
                                   ((jc ^ (row & 7)) * 16));
      }
#pragma unroll
      for (int im = 0; im < 4; im++)
#pragma unroll
        for (int in = 0; in < 4; in++)
          acc[im][in] = __builtin_amdgcn_mfma_f32_16x16x32_bf16(
              af[im], bfr[in], acc[im][in], 0, 0, 0);
    }
  }

#pragma unroll
  for (int im = 0; im < 4; im++) {
#pragma unroll
    for (int in = 0; in < 4; in++) {
      const int col = n0 + wave_n * 64 + in * 16 + (lane & 15);
#pragma unroll
      for (int r = 0; r < 4; r++) {
        const int row = m0 + wave_m * 64 + im * 16 + (lane >> 4) * 4 + r;
        float val = acc[im][in][r] + bias[col];
        if (MODE == 0) {
          if (col < DIM) {
            out0[(size_t)row * DIM + col] = f2bf(Bvec[col] * val);
          } else {
            const int d = col - DIM;
            const float s = 1.f / (1.f + __expf(-val));
            out1[(size_t)row * DIM + d] = f2bf(Avec[d] * s);
          }
        } else {
          out0[(size_t)row * DIM + col] = f2bf(val);
        }
      }
    }
  }
}

// ---------------- chunked scan ----------------
// h_t = a_t * h_{t-1} + bz_t, independent per (b,d) pair, t in [0,2048).

// Pass 1: per chunk, local scan from h=0; emit prod(a) and local h_end.
__global__ __launch_bounds__(256) void scan_pass1(
    const ushort_t* __restrict__ a_arr, const ushort_t* __restrict__ bz_arr,
    float* __restrict__ pout, float* __restrict__ hout) {
  const int tid = blockIdx.x * 256 + threadIdx.x;  // 64*4096 threads
  const int c = tid >> 12;
  const int q = tid & 4095;
  size_t base = (size_t)(c * CLEN) * BD + q * 4;
  float h0 = 0.f, h1 = 0.f, h2 = 0.f, h3 = 0.f;
  float p0 = 1.f, p1 = 1.f, p2 = 1.f, p3 = 1.f;
#pragma unroll 8
  for (int t = 0; t < CLEN; t++) {
    ushort4v av = *(const ushort4v*)(a_arr + base + (size_t)t * BD);
    ushort4v bv = *(const ushort4v*)(bz_arr + base + (size_t)t * BD);
    float a0 = bf2f(av.x), a1 = bf2f(av.y), a2 = bf2f(av.z), a3 = bf2f(av.w);
    h0 = a0 * h0 + bf2f(bv.x); p0 *= a0;
    h1 = a1 * h1 + bf2f(bv.y); p1 *= a1;
    h2 = a2 * h2 + bf2f(bv.z); p2 *= a2;
    h3 = a3 * h3 + bf2f(bv.w); p3 *= a3;
  }
  const size_t ci = (size_t)c * BD + q * 4;
  *(floatx4*)(pout + ci) = (floatx4){p0, p1, p2, p3};
  *(floatx4*)(hout + ci) = (floatx4){h0, h1, h2, h3};
}

// Pass 2: sequentially combine chunk carries; carry[c] = h entering chunk c.
__global__ __launch_bounds__(256) void scan_pass2(
    const float* __restrict__ p, const float* __restrict__ hend,
    float* __restrict__ carry) {
  const int q = blockIdx.x * 256 + threadIdx.x;  // 4096 threads
  float h0 = 0.f, h1 = 0.f, h2 = 0.f, h3 = 0.f;
  for (int c = 0; c < NCHUNK; c++) {
    const size_t ci = (size_t)c * BD + q * 4;
    floatx4 pv = *(const floatx4*)(p + ci);
    floatx4 hv = *(const floatx4*)(hend + ci);
    *(floatx4*)(carry + ci) = (floatx4){h0, h1, h2, h3};
    h0 = hv.x + pv.x * h0;
    h1 = hv.y + pv.y * h1;
    h2 = hv.z + pv.z * h2;
    h3 = hv.w + pv.w * h3;
  }
}

// Pass 3: re-scan each chunk with its carry-in, write h (bf16).
__global__ __launch_bounds__(256) void scan_pass3(
    const ushort_t* __restrict__ a_arr, const ushort_t* __restrict__ bz_arr,
    const float* __restrict__ carry, ushort_t* __restrict__ h_arr) {
  const int tid = blockIdx.x * 256 + threadIdx.x;
  const int c = tid >> 12;
  const int q = tid & 4095;
  size_t base = (size_t)(c * CLEN) * BD + q * 4;
  const size_t ci = (size_t)c * BD + q * 4;
  floatx4 cv = *(const floatx4*)(carry + ci);
  float h0 = cv.x, h1 = cv.y, h2 = cv.z, h3 = cv.w;
#pragma unroll 8
  for (int t = 0; t < CLEN; t++) {
    ushort4v av = *(const ushort4v*)(a_arr + base + (size_t)t * BD);
    ushort4v bv = *(const ushort4v*)(bz_arr + base + (size_t)t * BD);
    h0 = bf2f(av.x) * h0 + bf2f(bv.x);
    h1 = bf2f(av.y) * h1 + bf2f(bv.y);
    h2 = bf2f(av.z) * h2 + bf2f(bv.z);
    h3 = bf2f(av.w) * h3 + bf2f(bv.w);
    ushort4v o;
    o.x = f2bf(h0); o.y = f2bf(h1); o.z = f2bf(h2); o.w = f2bf(h3);
    *(ushort4v*)(h_arr + base + (size_t)t * BD) = o;
  }
}

// ---------------- residual + layernorm ----------------
// One wave per row of 512; lane handles 8 consecutive cols.
__global__ __launch_bounds__(256) void ln_kernel(
    const float* __restrict__ x, const ushort_t* __restrict__ op,
    const float* __restrict__ gamma, const float* __restrict__ beta,
    float* __restrict__ y) {
  const int wid = threadIdx.x >> 6;
  const int lane = threadIdx.x & 63;
  const size_t row = (size_t)blockIdx.x * 4 + wid;
  const size_t base = row * DIM + lane * 8;
  floatx4 x0 = *(const floatx4*)(x + base);
  floatx4 x1 = *(const floatx4*)(x + base + 4);
  short8 ov = *(const short8*)(op + base);
  float v[8];
  v[0] = x0.x + bf2f((ushort_t)ov[0]);
  v[1] = x0.y + bf2f((ushort_t)ov[1]);
  v[2] = x0.z + bf2f((ushort_t)ov[2]);
  v[3] = x0.w + bf2f((ushort_t)ov[3]);
  v[4] = x1.x + bf2f((ushort_t)ov[4]);
  v[5] = x1.y + bf2f((ushort_t)ov[5]);
  v[6] = x1.z + bf2f((ushort_t)ov[6]);
  v[7] = x1.w + bf2f((ushort_t)ov[7]);
  float s = 0.f, ss = 0.f;
#pragma unroll
  for (int j = 0; j < 8; j++) {
    s += v[j];
    ss += v[j] * v[j];
  }
#pragma unroll
  for (int m = 32; m >= 1; m >>= 1) {
    s += __shfl_xor(s, m, 64);
    ss += __shfl_xor(ss, m, 64);
  }
  const float mean = s * (1.f / DIM);
  const float var = ss * (1.f / DIM) - mean * mean;
  const float rstd = rsqrtf(var + 1e-5f);
  const int cb = lane * 8;
  floatx4 o0, o1;
  o0.x = (v[0] - mean) * rstd * gamma[cb + 0] + beta[cb + 0];
  o0.y = (v[1] - mean) * rstd * gamma[cb + 1] + beta[cb + 1];
  o0.z = (v[2] - mean) * rstd * gamma[cb + 2] + beta[cb + 2];
  o0.w = (v[3] - mean) * rstd * gamma[cb + 3] + beta[cb + 3];
  o1.x = (v[4] - mean) * rstd * gamma[cb + 4] + beta[cb + 4];
  o1.y = (v[5] - mean) * rstd * gamma[cb + 5] + beta[cb + 5];
  o1.z = (v[6] - mean) * rstd * gamma[cb + 6] + beta[cb + 6];
  o1.w = (v[7] - mean) * rstd * gamma[cb + 7] + beta[cb + 7];
  *(floatx4*)(y + base) = o0;
  *(floatx4*)(y + base + 4) = o1;
}

// ---------------- launch ----------------
extern "C" void kernel_launch(void* const* d_in, const int* in_sizes, int n_in,
                              void* d_out, int out_size, void* d_ws,
                              size_t ws_size, hipStream_t stream) {
  const float* x = (const float*)d_in[0];
  const float* W_in = (const float*)d_in[1];
  const float* b_in = (const float*)d_in[2];
  const float* W_out = (const float*)d_in[3];
  const float* b_out = (const float*)d_in[4];
  const float* Avec = (const float*)d_in[5];
  const float* Bvec = (const float*)d_in[6];
  const float* gamma = (const float*)d_in[7];
  const float* beta = (const float*)d_in[8];
  float* out = (float*)d_out;

  char* ws = (char*)d_ws;
  const size_t SZ64 = (size_t)M_TOT * DIM * 2;  // 64 MiB
  ushort_t* xb = (ushort_t*)ws;                  // x bf16; later reused as h
  ushort_t* gA = (ushort_t*)(ws + SZ64);         // gate*A; later reused as out_ws
  ushort_t* bz = (ushort_t*)(ws + 2 * SZ64);     // B*z
  ushort_t* wib = (ushort_t*)(ws + 3 * SZ64);
  ushort_t* wob = (ushort_t*)(ws + 3 * SZ64 + (size_t)N1 * K_DIM * 2);
  char* p0 = ws + 3 * SZ64 + (size_t)N1 * K_DIM * 2 + (size_t)DIM * K_DIM * 2;
  float* pc = (float*)p0;                                   // 4 MiB
  float* hc = (float*)(p0 + (size_t)NCHUNK * BD * 4);       // 4 MiB
  float* cc = (float*)(p0 + 2 * (size_t)NCHUNK * BD * 4);   // 4 MiB

  // converts
  cvt_f32_bf16<<<(M_TOT * DIM / 4 + 255) / 256, 256, 0, stream>>>(
      x, xb, M_TOT * DIM / 4);
  cvt_f32_bf16<<<(N1 * K_DIM / 4 + 255) / 256, 256, 0, stream>>>(
      W_in, wib, N1 * K_DIM / 4);
  cvt_f32_bf16<<<(DIM * K_DIM / 4 + 255) / 256, 256, 0, stream>>>(
      W_out, wob, DIM * K_DIM / 4);

  // in_proj + gate epilogue (1-D swizzled grid: 512 m-tiles x 8 n-tiles)
  gemm_bt<0, 8><<<MT_TILES * 8, 256, 0, stream>>>(
      xb, wib, b_in, Avec, Bvec, bz, gA);

  // chunked scan
  scan_pass1<<<NCHUNK * (BD / 4) / 256, 256, 0, stream>>>(gA, bz, pc, hc);
  scan_pass2<<<(BD / 4) / 256, 256, 0, stream>>>(pc, hc, cc);
  scan_pass3<<<NCHUNK * (BD / 4) / 256, 256, 0, stream>>>(gA, bz, cc, xb);

  // out_proj (h = xb region, output into gA region; 512 m-tiles x 4 n-tiles)
  gemm_bt<1, 4><<<MT_TILES * 4, 256, 0, stream>>>(
      xb, wob, b_out, nullptr, nullptr, gA, nullptr);

  // residual + layernorm
  ln_kernel<<<M_TOT / 4, 256, 0, stream>>>(x, gA, gamma, beta, out);
}